// Round 11
// baseline (276.686 us; speedup 1.0000x reference)
//
#include <hip/hip_runtime.h>

// VQ: x (16,64,64,64) f32, codebook e (64,1024) f32. N=65536, D=64, K=1024.
//
// R11 = R6's proven clean loop (no staging, no pipelining, small live state)
// with fp16 2-term scoring + certified per-position margin:
//   dot ~= xh*eh + xl*eh   (x = xh + xl in fp16; e -> fp16 high only)
//   |approx_gap - np_gap| <= Sx_p*2.52e-4 + 3e-5  (e-rounding dominates)
//   margin_p = Sx_p*2.7e-4 + 1e-4 (Sx_p = sum_d |x_pd|, tracked in-kernel)
// Certified positions write the MFMA winner; ambiguous ones (~2-3%) are
// re-scored by the block-local np-bit-exact scan (R3-verified ordering).
// A-less scores (A_p constant per position); 2 dispatches total.

#define D 64
#define K 1024
#define NPOS 65536
#define HW 4096
#define XSTRIDE 262144  // D*HW

typedef float vfloat4 __attribute__((ext_vector_type(4)));
typedef _Float16 half8 __attribute__((ext_vector_type(8)));

// ---- prep: 64 blocks, one 16-code tile each; frags fp16-high only --------
__global__ __launch_bounds__(256)
void vq_prep(const float* __restrict__ e, half8* __restrict__ ebf,
             float* __restrict__ eT, float* __restrict__ c2) {
    __shared__ float et[64][17];
    const int tile = blockIdx.x;
    const int t = threadIdx.x;
    const int k0 = tile * 16;
#pragma unroll
    for (int it = 0; it < 4; ++it) {
        const int d = it * 16 + (t >> 4);
        et[d][t & 15] = e[d * K + k0 + (t & 15)];
    }
    __syncthreads();
    if (t < 128) {                       // frags: 2 K-halves x 64 lanes
        const int s = t >> 6;
        const int lane = t & 63;
        const int n = lane & 15, q = lane >> 4;
        half8 fh;
#pragma unroll
        for (int j = 0; j < 8; ++j) {
            const int d = s * 32 + q * 8 + j;   // B[k=q*8+j][n], k-chunk s
            fh[j] = (_Float16)et[d][n];         // RNE to fp16
        }
        ebf[(tile * 2 + s) * 64 + lane] = fh;   // 16 B coalesced store
    }
    {                                    // eT rows: coalesced vfloat4
        const int kk = t >> 4, d0 = (t & 15) * 4;
        vfloat4 v;
#pragma unroll
        for (int i = 0; i < 4; ++i) v[i] = et[d0 + i][kk];
        *(vfloat4*)(eT + (size_t)(k0 + kk) * 64 + d0) = v;
    }
    if (t < 16) {                        // c2: np axis-0 sequential order
        float s = 0.f;
#pragma unroll
        for (int d = 0; d < D; ++d) {
            const float v = et[d][t];
            s = s + __fmul_rn(v, v);
        }
        c2[k0 + t] = s;
    }
}

// ---- main: 512 blocks x 256; block = 128 pos; wave = 2 M-tiles, full K ---
__global__ __launch_bounds__(256, 2)
void vq_main(const float* __restrict__ x, const float* __restrict__ e,
             const half8* __restrict__ ebf, const float* __restrict__ eT,
             const float* __restrict__ c2g, float* __restrict__ out) {
    __shared__ float c2_lds[K];          // 4 KB
    __shared__ float bx[128];            // per-position sum|x| for margin
    __shared__ float q_lds[64][65];      // 16.6 KB
    __shared__ int   bk_lds[128];
    __shared__ int   amb_cnt, amb_list[128];
    __shared__ float xa[64];
    __shared__ float aSh;
    __shared__ float rs[256];
    __shared__ int   rk[256];

    const int t    = threadIdx.x;
    const int lane = t & 63;
    const int w    = t >> 6;
    const int n    = lane & 15;          // A-row m / B-col code
    const int q    = lane >> 4;          // k-quad / C row group
    const int p0   = blockIdx.x * 128;
    const int b    = p0 >> 12;
    const int sp0  = p0 & (HW - 1);

    if (t == 0) amb_cnt = 0;
    ((vfloat4*)c2_lds)[t] = ((const vfloat4*)c2g)[t];

    // ---- A-frags: fp16 hi/lo of this wave's 32 positions; track sum|x|
    half8 ah[2][2], al[2][2];
#pragma unroll
    for (int mt = 0; mt < 2; ++mt) {
        const int spc = sp0 + w * 32 + mt * 16 + n;
        float sx = 0.f;
#pragma unroll
        for (int s = 0; s < 2; ++s) {
            half8 fh, fl_;
#pragma unroll
            for (int j = 0; j < 8; ++j) {
                const int d = s * 32 + q * 8 + j;     // A[m=n][k=q*8+j]
                const float v = x[(size_t)b * XSTRIDE + (size_t)d * HW + spc];
                const _Float16 h = (_Float16)v;       // RNE
                fh[j] = h;
                fl_[j] = (_Float16)(v - (float)h);    // exact-ish residual
                sx += fabsf(v);
            }
            ah[mt][s] = fh; al[mt][s] = fl_;
        }
        sx += __shfl_xor(sx, 16, 64);    // sum over the 4 q-groups
        sx += __shfl_xor(sx, 32, 64);
        if (q == 0) bx[w * 32 + mt * 16 + n] = sx;
    }
    __syncthreads();                     // c2_lds + bx ready

    float s1v[2][4], s2v[2][4]; int t1v[2][4];
#pragma unroll
    for (int mt = 0; mt < 2; ++mt)
#pragma unroll
        for (int r = 0; r < 4; ++r) { s1v[mt][r] = 3.4e38f; s2v[mt][r] = 3.4e38f; t1v[mt][r] = 0; }

    // ---- barrier-free scan of all 64 tiles, frags straight from L2
    const half8* __restrict__ fp = ebf;
    for (int tile = 0; tile < 64; ++tile) {
        const half8 bh0 = fp[lane];              // K-chunk d=0..31
        const half8 bh1 = fp[64 + lane];         // K-chunk d=32..63
        fp += 128;
        const float c2v = c2_lds[tile * 16 + n];
#pragma unroll
        for (int mt = 0; mt < 2; ++mt) {
            vfloat4 acc = {0.f, 0.f, 0.f, 0.f};
            acc = __builtin_amdgcn_mfma_f32_16x16x32_f16(ah[mt][0], bh0, acc, 0, 0, 0);
            acc = __builtin_amdgcn_mfma_f32_16x16x32_f16(ah[mt][1], bh1, acc, 0, 0, 0);
            acc = __builtin_amdgcn_mfma_f32_16x16x32_f16(al[mt][0], bh0, acc, 0, 0, 0);
            acc = __builtin_amdgcn_mfma_f32_16x16x32_f16(al[mt][1], bh1, acc, 0, 0, 0);
#pragma unroll
            for (int r = 0; r < 4; ++r) {        // top-2, s1<=s2 invariant
                const float sc = __builtin_fmaf(-2.f, acc[r], c2v);
                const bool lt1 = sc < s1v[mt][r];
                s2v[mt][r] = __builtin_amdgcn_fmed3f(sc, s1v[mt][r], s2v[mt][r]);
                s1v[mt][r] = fminf(s1v[mt][r], sc);
                t1v[mt][r] = lt1 ? tile : t1v[mt][r];
            }
        }
    }

    // ---- butterfly top-2 over 16 code-columns; certify per position
#pragma unroll
    for (int mt = 0; mt < 2; ++mt)
#pragma unroll
        for (int r = 0; r < 4; ++r) {
            float a1 = s1v[mt][r], a2 = s2v[mt][r];
            int ak = t1v[mt][r] * 16 + n;
#pragma unroll
            for (int m = 1; m < 16; m <<= 1) {
                const float o1 = __shfl_xor(a1, m, 64);
                const float o2 = __shfl_xor(a2, m, 64);
                const int   ok = __shfl_xor(ak, m, 64);
                const bool take = (o1 < a1) || (o1 == a1 && ok < ak);
                const float loser = take ? a1 : o1;
                a1 = take ? o1 : a1;
                ak = take ? ok : ak;
                a2 = fminf(fminf(a2, o2), loser);
            }
            if (n == 0) {
                const int pl = w * 32 + mt * 16 + q * 4 + r;   // C row=q*4+r
                bk_lds[pl] = ak;
                const float margin = __builtin_fmaf(bx[pl], 2.7e-4f, 1.0e-4f);
                if (a2 - a1 <= margin) {               // uncertified
                    const int i = atomicAdd(&amb_cnt, 1);
                    amb_list[i] = pl;
                }
            }
        }
    __syncthreads();

    // ---- epilogue: 2 half-rounds of 64 positions through q_lds
#pragma unroll
    for (int half = 0; half < 2; ++half) {
        {
            const int row = t >> 2, seg = t & 3;
            const float* er = eT + (size_t)bk_lds[half * 64 + row] * 64 + seg * 16;
#pragma unroll
            for (int i = 0; i < 4; ++i)
                *(vfloat4*)(&q_lds[row][seg * 16 + i * 4]) = *(const vfloat4*)(er + i * 4);
        }
        __syncthreads();
        {
            const int pl = t & 63, grp = t >> 6;
            const int sp = sp0 + half * 64 + pl;
            const float* xb = x + (size_t)b * XSTRIDE + sp;
            float* ob = out + (size_t)b * XSTRIDE + sp;
#pragma unroll
            for (int i = 0; i < 16; ++i) {
                const int c = grp * 16 + i;
                const float xq = xb[(size_t)c * HW];
                const float qv = q_lds[pl][c];
                ob[(size_t)c * HW] = xq + (qv - xq);   // np STE
            }
        }
        __syncthreads();
    }

    // ---- block-local np-bit-exact fallback (ambiguous positions only)
    const int na = amb_cnt;
    for (int ai = 0; ai < na; ++ai) {
        const int pl = amb_list[ai];
        const int sp = sp0 + pl;
        if (t < 64) xa[t] = x[(size_t)b * XSTRIDE + (size_t)t * HW + sp];
        __syncthreads();
        if (t == 0) {                    // np A: pairwise-8, rounded squares
            float r8[8];
#pragma unroll
            for (int i = 0; i < 8; ++i) r8[i] = __fmul_rn(xa[i], xa[i]);
#pragma unroll
            for (int j = 1; j < 8; ++j)
#pragma unroll
                for (int i = 0; i < 8; ++i)
                    r8[i] = r8[i] + __fmul_rn(xa[8 * j + i], xa[8 * j + i]);
            aSh = ((r8[0]+r8[1])+(r8[2]+r8[3])) + ((r8[4]+r8[5])+(r8[6]+r8[7]));
        }
        __syncthreads();
        const float Ap = aSh;
        float bs = 3.4e38f; int bkk = 0x7fffffff;
#pragma unroll
        for (int j = 0; j < 4; ++j) {
            const int k = t + 256 * j;                 // ascending k
            float acc = 0.f;
            for (int d = 0; d < D; ++d)                // sequential-d chain
                acc = __builtin_fmaf(xa[d], e[d * K + k], acc);
            const float sc = __builtin_fmaf(-2.f, acc, Ap) + c2_lds[k];
            if (sc < bs || (sc == bs && k < bkk)) { bs = sc; bkk = k; }
        }
        rs[t] = bs; rk[t] = bkk;
        __syncthreads();
        for (int off = 128; off > 0; off >>= 1) {
            if (t < off) {
                const float so = rs[t + off]; const int ko = rk[t + off];
                if (so < rs[t] || (so == rs[t] && ko < rk[t])) { rs[t] = so; rk[t] = ko; }
            }
            __syncthreads();
        }
        const int kb = rk[0];
        if (t < 64) {
            const float xq = xa[t];
            const float qv = eT[(size_t)kb * 64 + t];
            out[(size_t)b * XSTRIDE + (size_t)t * HW + sp] = xq + (qv - xq);
        }
        __syncthreads();
    }
}

extern "C" void kernel_launch(void* const* d_in, const int* in_sizes, int n_in,
                              void* d_out, int out_size, void* d_ws, size_t ws_size,
                              hipStream_t stream) {
    const float* x = (const float*)d_in[0];
    const float* e = (const float*)d_in[1];
    float* out = (float*)d_out;

    char* ws = (char*)d_ws;                          // 392 KB used
    half8* ebf = (half8*)ws;                         // 128 KB fp16 B-frags
    float* eT = (float*)(ws + 131072);               // 256 KB fp32 rows
    float* c2 = (float*)(ws + 393216);               // 4 KB

    vq_prep<<<64, 256, 0, stream>>>(e, ebf, eT, c2);
    vq_main<<<NPOS / 128, 256, 0, stream>>>(x, e, ebf, eT, c2, out);
}